// Round 4
// baseline (72.461 us; speedup 1.0000x reference)
//
#include <hip/hip_runtime.h>
#include <hip/hip_bf16.h>

#define D 8192
#define NPAIR 523776.0

typedef short short8 __attribute__((ext_vector_type(8)));
typedef float f32x4 __attribute__((ext_vector_type(4)));

__device__ __forceinline__ short8 cvt8(const float4 a, const float4 b) {
    union { short8 s; __hip_bfloat162 h[4]; } u;
    u.h[0] = __float22bfloat162_rn(make_float2(a.x, a.y));
    u.h[1] = __float22bfloat162_rn(make_float2(a.z, a.w));
    u.h[2] = __float22bfloat162_rn(make_float2(b.x, b.y));
    u.h[3] = __float22bfloat162_rn(make_float2(b.z, b.w));
    return u.s;
}

// 1024 blocks, bid = x(0..7, XCD slot) + 8*s.  m = x>>2, xr = x&3.
// DIAG FIRST (they do 2x the steps -> start them at t=0 to kill the tail):
//   s < 16 : diag tiles. dt = s&7, c = (s>>3)*4 + xr (8 chunks of K=1024, 32 steps)
//   s >= 16: off-diag.  sp = s-16: c = (sp/28)*4 + xr (16 chunks of K=512, 16 steps),
//            tt = sp%28 -> triangular pair (ti,tj)
__device__ __forceinline__ void decode_bid(int bid, int& m, int& ti, int& tj, int& k0, int& nsteps) {
    int x = bid & 7, s = bid >> 3;
    m = x >> 2;
    int xr = x & 3;
    if (s < 16) {
        ti = tj = s & 7;
        int c = ((s >> 3) << 2) + xr;
        k0 = c * 1024; nsteps = 32;
    } else {
        int sp = s - 16;
        int c = (sp / 28) * 4 + xr;
        int tt = sp % 28;
        int a = 0;
        while (tt >= 7 - a) { tt -= 7 - a; ++a; }
        ti = a; tj = a + 1 + tt;
        k0 = c * 512; nsteps = 16;
    }
}
__device__ __forceinline__ int bid_off(int m, int tt, int c) {
    return (m * 4 + (c & 3)) + ((16 + (c >> 2) * 28 + tt) << 3);
}
__device__ __forceinline__ int bid_diag(int m, int dt, int c) {
    return (m * 4 + (c & 3)) + ((((c >> 2) << 3) + dt) << 3);
}

template<bool STORE>
__global__ __launch_bounds__(512, 4)
void gram_kernel(const float* __restrict__ pred, const float* __restrict__ tgt,
                 float* __restrict__ out, float* __restrict__ norms) {
    int m, ti, tj, k0, nsteps;
    decode_bid(blockIdx.x, m, ti, tj, k0, nsteps);
    const bool same = (ti == tj);
    const float* __restrict__ x = m ? tgt : pred;

    __shared__ short lsA[2][4096];   // [128 rows][32 k] bf16, XOR-swizzled 16B slots
    __shared__ short lsB[2][4096];

    const int tid = threadIdx.x;
    const int lane = tid & 63;
    const int wid = tid >> 6;
    const int wr = wid >> 2, wc = wid & 3;   // 8 waves: 2x4 grid of 64x32 wave tiles

    // staging: one 8-float slot per thread per matrix: row = tid>>2, k-slot = tid&3
    const int srow = tid >> 2, sc8 = tid & 3;
    const float* __restrict__ gA = x + (size_t)(ti * 128 + srow) * D + k0 + sc8 * 8;
    const float* __restrict__ gB = x + (size_t)(tj * 128 + srow) * D + k0 + sc8 * 8;
    const int wby = srow * 64 + ((sc8 ^ ((srow >> 1) & 3)) << 4);  // swizzled LDS byte offset

    // fragment read offsets (swizzle-consistent: 16/64-row strides don't touch (row>>1)&3)
    const int rbA = (wr * 64 + (lane & 15)) * 64;
    const int rbB = (wc * 32 + (lane & 15)) * 64;
    const int kby = (((lane >> 4) ^ (((lane & 15) >> 1) & 3)) << 4);

    f32x4 zero = {0.f, 0.f, 0.f, 0.f};
    f32x4 acc[4][2];
#pragma unroll
    for (int mi = 0; mi < 4; ++mi) { acc[mi][0] = zero; acc[mi][1] = zero; }

    float4 ra0, ra1, rb0, rb1;
    // prologue: load step0, write buf0, load step1
    { const float4* p = (const float4*)gA; ra0 = p[0]; ra1 = p[1];
      if (!same) { const float4* q = (const float4*)gB; rb0 = q[0]; rb1 = q[1]; } }
    *(short8*)((char*)lsA[0] + wby) = cvt8(ra0, ra1);
    if (!same) *(short8*)((char*)lsB[0] + wby) = cvt8(rb0, rb1);
    { const float4* p = (const float4*)(gA + 32); ra0 = p[0]; ra1 = p[1];
      if (!same) { const float4* q = (const float4*)(gB + 32); rb0 = q[0]; rb1 = q[1]; } }
    asm volatile("s_waitcnt lgkmcnt(0)" ::: "memory");
    __builtin_amdgcn_s_barrier();

    for (int step = 0; step < nsteps; ++step) {
        const int cur = step & 1;
        const short* __restrict__ bufA = lsA[cur];
        const short* __restrict__ bufB = same ? lsA[cur] : lsB[cur];

        // compute first (depends only on the barrier), stage-write late (T14)
        __builtin_amdgcn_s_setprio(1);
        short8 bf0 = *(const short8*)((const char*)bufB + (rbB + kby));
        short8 bf1 = *(const short8*)((const char*)bufB + (rbB + 1024 + kby));
#pragma unroll
        for (int mi = 0; mi < 4; ++mi) {
            short8 af = *(const short8*)((const char*)bufA + (rbA + mi * 1024 + kby));
            acc[mi][0] = __builtin_amdgcn_mfma_f32_16x16x32_bf16(af, bf0, acc[mi][0], 0, 0, 0);
            acc[mi][1] = __builtin_amdgcn_mfma_f32_16x16x32_bf16(af, bf1, acc[mi][1], 0, 0, 0);
        }
        __builtin_amdgcn_s_setprio(0);

        if (step + 1 < nsteps) {
            const int nxt = cur ^ 1;
            *(short8*)((char*)lsA[nxt] + wby) = cvt8(ra0, ra1);
            if (!same) *(short8*)((char*)lsB[nxt] + wby) = cvt8(rb0, rb1);
            if (step + 2 < nsteps) {   // prefetch; stays in flight across the barrier
                const float4* p = (const float4*)(gA + (step + 2) * 32);
                ra0 = p[0]; ra1 = p[1];
                if (!same) { const float4* q = (const float4*)(gB + (step + 2) * 32); rb0 = q[0]; rb1 = q[1]; }
            }
        }
        asm volatile("s_waitcnt lgkmcnt(0)" ::: "memory");
        __builtin_amdgcn_s_barrier();
    }

    if (STORE) {
        float* __restrict__ dst = out + (size_t)blockIdx.x * 16384;
#pragma unroll
        for (int mi = 0; mi < 4; ++mi)
#pragma unroll
            for (int ni = 0; ni < 2; ++ni)
#pragma unroll
                for (int r = 0; r < 4; ++r) {
                    int li = wr * 64 + mi * 16 + (lane >> 4) * 4 + r;
                    int lj = wc * 32 + ni * 16 + (lane & 15);
                    dst[li * 128 + lj] = acc[mi][ni][r];
                    // norms from diag-tile diagonals (norms buffer zeroed by memsetAsync)
                    if (same && li == lj)
                        atomicAdd(&norms[m * 1024 + ti * 128 + li], acc[mi][ni][r]);
                }
    } else {
        float* __restrict__ g = out + (size_t)m * (1024 * 1024);
#pragma unroll
        for (int mi = 0; mi < 4; ++mi)
#pragma unroll
            for (int ni = 0; ni < 2; ++ni)
#pragma unroll
                for (int r = 0; r < 4; ++r) {
                    int gi = ti * 128 + wr * 64 + mi * 16 + (lane >> 4) * 4 + r;
                    int gj = tj * 128 + wc * 32 + ni * 16 + (lane & 15);
                    atomicAdd(&g[gi * 1024 + gj], acc[mi][ni][r]);
                }
    }
}

// store path: each thread handles 4 consecutive j for one i (float4 gathers),
// block partial -> atomicAdd into d_out (memset to 0 at launch).
__global__ __launch_bounds__(256)
void loss_store_kernel(const float* __restrict__ part, const float* __restrict__ norms,
                       float* __restrict__ out) {
    const int tid = threadIdx.x;
    const int qid = blockIdx.x * 256 + tid;     // 0..262143
    const int i = qid >> 8;
    const int j0 = (qid & 255) << 2;
    float local = 0.f;
    const int ti = i >> 7, tj = j0 >> 7;
    if (tj > ti || (tj == ti && j0 + 3 > i)) {
        const int el = ((i & 127) << 7) + (j0 & 127);
        f32x4 gp = {0.f, 0.f, 0.f, 0.f}, gt = {0.f, 0.f, 0.f, 0.f};
        if (ti == tj) {
#pragma unroll
            for (int c = 0; c < 8; ++c) {
                gp += *(const f32x4*)&part[(size_t)bid_diag(0, ti, c) * 16384 + el];
                gt += *(const f32x4*)&part[(size_t)bid_diag(1, ti, c) * 16384 + el];
            }
        } else {
            int tt = 7 * ti - (ti * (ti - 1)) / 2 + (tj - ti - 1);
#pragma unroll
            for (int c = 0; c < 16; ++c) {
                gp += *(const f32x4*)&part[(size_t)bid_off(0, tt, c) * 16384 + el];
                gt += *(const f32x4*)&part[(size_t)bid_off(1, tt, c) * 16384 + el];
            }
        }
        const float nip = norms[i], nit = norms[1024 + i];
#pragma unroll
        for (int e = 0; e < 4; ++e) {
            int j = j0 + e;
            if (j > i) {
                float dp = nip + norms[j] - 2.f * gp[e];
                float dt = nit + norms[1024 + j] - 2.f * gt[e];
                float c2 = sqrtf(fmaxf(dp, 0.f)) - sqrtf(fmaxf(dt, 0.f));
                local += c2 * c2;
            }
        }
    }
#pragma unroll
    for (int off = 32; off > 0; off >>= 1) local += __shfl_down(local, off);
    __shared__ float wsum[4];
    if ((tid & 63) == 0) wsum[tid >> 6] = local;
    __syncthreads();
    if (tid == 0) atomicAdd(out, (float)((wsum[0] + wsum[1] + wsum[2] + wsum[3]) / NPAIR));
}

// fallback loss (atomic gram path): reads dense gram[2][1024][1024]
__global__ __launch_bounds__(256)
void loss_atomic_kernel(const float* __restrict__ gram, float* __restrict__ out) {
    const float* __restrict__ gP = gram;
    const float* __restrict__ gT = gram + 1024 * 1024;
    const int tid = threadIdx.x;
    const int base = blockIdx.x * 256 + tid;
    float local = 0.f;
#pragma unroll
    for (int s = 0; s < 4; ++s) {
        int lin = base + s * 262144;
        int i = lin >> 10, j = lin & 1023;
        if (j > i) {
            float dp = gP[i * 1024 + i] + gP[j * 1024 + j] - 2.f * gP[lin];
            float dt = gT[i * 1024 + i] + gT[j * 1024 + j] - 2.f * gT[lin];
            float c = sqrtf(fmaxf(dp, 0.f)) - sqrtf(fmaxf(dt, 0.f));
            local += c * c;
        }
    }
#pragma unroll
    for (int off = 32; off > 0; off >>= 1) local += __shfl_down(local, off);
    __shared__ float wsum[4];
    if ((tid & 63) == 0) wsum[tid >> 6] = local;
    __syncthreads();
    if (tid == 0) atomicAdd(out, (float)((wsum[0] + wsum[1] + wsum[2] + wsum[3]) / NPAIR));
}

extern "C" void kernel_launch(void* const* d_in, const int* in_sizes, int n_in,
                              void* d_out, int out_size, void* d_ws, size_t ws_size,
                              hipStream_t stream) {
    const float* pred = (const float*)d_in[0];
    const float* tgt  = (const float*)d_in[1];
    float* ws = (float*)d_ws;
    hipMemsetAsync(d_out, 0, sizeof(float), stream);
    const size_t need = ((size_t)1024 * 16384 + 2048) * 4;
    if (ws_size >= need) {
        float* part  = ws;                           // 1024 x 16384 f32 = 67.1 MB
        float* norms = ws + (size_t)1024 * 16384;    // 2048 f32
        hipMemsetAsync(norms, 0, 2048 * sizeof(float), stream);
        gram_kernel<true><<<1024, 512, 0, stream>>>(pred, tgt, part, norms);
        loss_store_kernel<<<1024, 256, 0, stream>>>(part, norms, (float*)d_out);
    } else {
        float* gram = ws;                            // 2 x 1024 x 1024 f32 = 8 MB
        hipMemsetAsync(gram, 0, (size_t)2 * 1024 * 1024 * sizeof(float), stream);
        gram_kernel<false><<<1024, 512, 0, stream>>>(pred, tgt, gram, nullptr);
        loss_atomic_kernel<<<1024, 256, 0, stream>>>(gram, (float*)d_out);
    }
}